// Round 11
// baseline (1212.359 us; speedup 1.0000x reference)
//
#include <hip/hip_runtime.h>

// Volume dims (fixed by the reference): frames[T=3][Z=72][Y=512][X=1024], fp32.
#define TT 3
#define ZZ 72
#define YY 512
#define XX 1024
#define FRAME_STRIDE ((long)ZZ * YY * XX)   // 37,748,736 elements
#define ZSTRIDE      ((long)YY * XX)        // 524,288
#define YSTRIDE      ((long)XX)             // 1,024

// Bucketing: key = z0 * 8 + (y0 >> 6)  → 72 * 8 = 576 buckets.
// Window per bucket: 2 z-slabs × 65 y-rows × 1024 x × 3 frames ≈ 1.6 MB.
#define NB    576
// Fixed slots per bucket. Uniform mean = N/NB = 7282, sd ≈ 85 → 8192 = +10.7σ.
// Overflow items are sampled INLINE in the bin pass (correct for any distribution).
#define CAP   8192
#define MBPB  (CAP / 256)   // main-pass blocks per bucket = 32
// One global counter per 64B line.
#define CPAD  16
#define IPT   16            // items per thread in the bin pass
#define WARM  1             // sequential pre-touch of each bucket's fresh slab

// Native clang vector for nontemporal builtins (HIP float4 is a struct and
// is rejected by __builtin_nontemporal_* — R7 compile failure).
typedef float vfloat4 __attribute__((ext_vector_type(4)));

__device__ __forceinline__ void nt_store_f4(float4 v, float4* p) {
    vfloat4 t = {v.x, v.y, v.z, v.w};
    __builtin_nontemporal_store(t, (vfloat4*)p);
}
__device__ __forceinline__ float4 nt_load_f4(const float4* p) {
    vfloat4 t = __builtin_nontemporal_load((const vfloat4*)p);
    return make_float4(t.x, t.y, t.z, t.w);
}

// ---------------------------------------------------------------------------
// Pair-load trilerp: x0/x1 are adjacent → 4 float2 loads per frame instead of
// 8 scalar gathers (main is request-throughput-bound: 28% BW, 6% VALU).
// x0 == XX-1 (wx == 0): load at XX-2, use .y for both taps — exact ref math.
// ---------------------------------------------------------------------------
__device__ __forceinline__ float2 ld2(const float* __restrict__ p) {
    float2 v;
    __builtin_memcpy(&v, p, sizeof(float2));   // 4B-aligned 8B load (gfx950 ok)
    return v;
}

__device__ __forceinline__ float trilerp_frame(
    const float* __restrict__ fr,
    long oz0y0, long oz0y1, long oz1y0, long oz1y1,
    int xl, bool xhi, float wz, float wy, float wx)
{
    float2 a = ld2(fr + oz0y0 + xl);
    float2 b = ld2(fr + oz0y1 + xl);
    float2 c = ld2(fr + oz1y0 + xl);
    float2 d = ld2(fr + oz1y1 + xl);
    float c000 = xhi ? a.y : a.x, c001 = a.y;
    float c010 = xhi ? b.y : b.x, c011 = b.y;
    float c100 = xhi ? c.y : c.x, c101 = c.y;
    float c110 = xhi ? d.y : d.x, c111 = d.y;
    float iwx = 1.0f - wx;
    float c00 = c000 * iwx + c001 * wx;
    float c01 = c010 * iwx + c011 * wx;
    float c10 = c100 * iwx + c101 * wx;
    float c11 = c110 * iwx + c111 * wx;
    float iwy = 1.0f - wy;
    float c0 = c00 * iwy + c01 * wy;
    float c1 = c10 * iwy + c11 * wy;
    return c0 * (1.0f - wz) + c1 * wz;
}

__device__ __forceinline__ float sample_one(float4 c, const float* __restrict__ frames)
{
    // temporal
    float t_abs = c.w * 3.0f;
    int t0 = (int)floorf(t_abs);
    t0 = min(max(t0, 0), TT - 1);
    float w = t_abs - (float)t0;
    int t1 = min(t0 + 1, TT - 1);

    // spatial
    float sz = c.x * (float)(ZZ - 1);
    float sy = c.y * (float)(YY - 1);
    float sx = c.z * (float)(XX - 1);
    int z0 = (int)sz;
    int y0 = (int)sy;
    int x0 = (int)sx;
    float wz = sz - (float)z0;   // weights from UNclamped idx (ref semantics)
    float wy = sy - (float)y0;
    float wx = sx - (float)x0;
    z0 = min(max(z0, 0), ZZ - 1);
    y0 = min(max(y0, 0), YY - 1);
    x0 = min(max(x0, 0), XX - 1);
    int z1 = min(z0 + 1, ZZ - 1);
    int y1 = min(y0 + 1, YY - 1);

    int  xl  = min(x0, XX - 2);
    bool xhi = (x0 == XX - 1);

    long oz0y0 = (long)z0 * ZSTRIDE + (long)y0 * YSTRIDE;
    long oz0y1 = (long)z0 * ZSTRIDE + (long)y1 * YSTRIDE;
    long oz1y0 = (long)z1 * ZSTRIDE + (long)y0 * YSTRIDE;
    long oz1y1 = (long)z1 * ZSTRIDE + (long)y1 * YSTRIDE;

    const float* f0 = frames + (long)t0 * FRAME_STRIDE;
    float v0 = trilerp_frame(f0, oz0y0, oz0y1, oz1y0, oz1y1, xl, xhi, wz, wy, wx);

    float v1;
    if (t1 != t0) {
        const float* f1 = frames + (long)t1 * FRAME_STRIDE;
        v1 = trilerp_frame(f1, oz0y0, oz0y1, oz1y0, oz1y1, xl, xhi, wz, wy, wx);
    } else {
        v1 = v0;   // t_abs in [2,3): both samples identical — skip 4 pair-loads
    }
    return v0 * (1.0f - w) + v1 * w;
}

__device__ __forceinline__ int bucket_key(float4 c)
{
    int z0 = (int)(c.x * (float)(ZZ - 1));
    int y0 = (int)(c.y * (float)(YY - 1));
    z0 = min(max(z0, 0), ZZ - 1);
    y0 = min(max(y0, 0), YY - 1);
    return z0 * 8 + (y0 >> 6);
}

// ---------------------------------------------------------------------------
// Pass 0: zero the padded counters (capture-safe, replay-idempotent).
// ---------------------------------------------------------------------------
__global__ __launch_bounds__(1024) void zero_counts_kernel(int* __restrict__ counts)
{
    int t = threadIdx.x;
    if (t < NB) counts[t * CPAD] = 0;
}

// ---------------------------------------------------------------------------
// Pass 1: fused binning. Stores the full coord record + original index per
// slot (both read SEQUENTIALLY by main — no coords re-gather, no rank array,
// no permute pass). Record/index writes are NON-TEMPORAL: consumed only by
// the next kernel, so don't let 94 MB of scattered stores churn L2.
// Overflow (slot >= CAP): sample inline.
// ---------------------------------------------------------------------------
__global__ __launch_bounds__(256) void bin_kernel(
    const float4* __restrict__ coords, int n,
    int*    __restrict__ counts,     // NB padded counters (zeroed by pass 0)
    float4* __restrict__ scoords,    // NB*CAP coord records
    int*    __restrict__ sidx,       // NB*CAP original indices
    const float* __restrict__ frames, float* __restrict__ out)
{
    __shared__ int lcnt[NB];
    __shared__ int lbase[NB];
    for (int k = threadIdx.x; k < NB; k += 256) lcnt[k] = 0;
    __syncthreads();

    int base_i = blockIdx.x * (256 * IPT) + threadIdx.x;
    float4 cs[IPT];
    int keys[IPT];
    int ranks[IPT];
#pragma unroll
    for (int j = 0; j < IPT; ++j) {
        int i = base_i + j * 256;
        if (i < n) {
            cs[j]    = coords[i];
            keys[j]  = bucket_key(cs[j]);
            ranks[j] = atomicAdd(&lcnt[keys[j]], 1);
        }
    }
    __syncthreads();
    for (int k = threadIdx.x; k < NB; k += 256) {
        int c = lcnt[k];
        lbase[k] = c ? atomicAdd(&counts[k * CPAD], c) : 0;
    }
    __syncthreads();
#pragma unroll
    for (int j = 0; j < IPT; ++j) {
        int i = base_i + j * 256;
        if (i < n) {
            int s = lbase[keys[j]] + ranks[j];
            if (s < CAP) {
                int g = keys[j] * CAP + s;
                nt_store_f4(cs[j], &scoords[g]);
                __builtin_nontemporal_store(i, &sidx[g]);
            } else {
                out[i] = sample_one(cs[j], frames);   // cold path
            }
        }
    }
}

// ---------------------------------------------------------------------------
// Pass 2: sampling in bucket order. Each bucket's 32 blocks sequentially
// pre-touch a disjoint 1/32 slice of the bucket's FRESH slab (zg+1, 3 frames,
// 64 rows = 768 KB) — sequentializes the HBM first-touch stream (R5: 440→342
// with this + sequential records). Then sample records sequentially (NT loads
// keep L2 for the frame window) and scatter out[sidx[g]] directly.
// ---------------------------------------------------------------------------
__global__ __launch_bounds__(256) void main_kernel(
    const float4* __restrict__ scoords, const int* __restrict__ sidx,
    const int*    __restrict__ counts,  const float* __restrict__ frames,
    float* __restrict__ out)
{
    int nwg  = gridDim.x;                 // NB*MBPB = 18432 (divisible by 8)
    int orig = blockIdx.x;
    int xcd  = orig & 7;
    int q = nwg >> 3, r = nwg & 7;
    int wg = (xcd < r ? xcd * (q + 1) : r * (q + 1) + (xcd - r) * q) + (orig >> 3);

    int bucket = wg / MBPB;
    int br     = wg % MBPB;               // this block's rank within the bucket

#if WARM
    {
        int zg = bucket >> 3;
        int yg = bucket & 7;
        int zs = (zg + 1 < ZZ) ? (zg + 1) : (ZZ - 1);
        float acc = 0.0f;
        int npass = (zg == 0) ? 2 : 1;    // z=0 buckets also warm slab 0
        for (int pass = 0; pass < npass; ++pass) {
            int zslab = pass ? 0 : zs;
            // fresh region: 3 frames x 64 rows x 256 float4 = 49152 float4
            // slice br: 1536 float4; per thread: 6
#pragma unroll
            for (int k = 0; k < 6; ++k) {
                int idx4 = br * 1536 + k * 256 + (int)threadIdx.x;
                int f    = idx4 >> 14;          // / (64*256)
                int rem  = idx4 & 16383;
                int ry   = rem >> 8;
                int c4   = rem & 255;
                const float* p = frames + (long)f * FRAME_STRIDE
                               + (long)zslab * ZSTRIDE
                               + (long)(yg * 64 + ry) * YSTRIDE
                               + (long)(c4 * 4);
                float4 v = *(const float4*)p;
                acc += v.x + v.y + v.z + v.w;
            }
        }
        asm volatile("" :: "v"(acc));       // keep warm loads live
    }
#endif

    int cnt = min(counts[bucket * CPAD], CAP);
    int slot = br * 256 + threadIdx.x;
    if (slot >= cnt) return;

    int g = bucket * CAP + slot;
    float4 c = nt_load_f4(&scoords[g]);
    int    j = __builtin_nontemporal_load(&sidx[g]);
    out[j] = sample_one(c, frames);
}

// ---------------------------------------------------------------------------
// Fallback: direct kernel (used only if workspace missing/too small).
// ---------------------------------------------------------------------------
__global__ __launch_bounds__(256) void direct_kernel(
    const float4* __restrict__ coords, const float* __restrict__ frames,
    float* __restrict__ out, int n)
{
    int i = blockIdx.x * blockDim.x + threadIdx.x;
    if (i >= n) return;
    out[i] = sample_one(coords[i], frames);
}

extern "C" void kernel_launch(void* const* d_in, const int* in_sizes, int n_in,
                              void* d_out, int out_size, void* d_ws, size_t ws_size,
                              hipStream_t stream) {
    const float4* coords = (const float4*)d_in[0];   // N*4 floats
    const float*  frames = (const float*)d_in[1];    // T*Z*Y*X floats
    float* out = (float*)d_out;                      // N floats
    int n = in_sizes[0] / 4;

    // Workspace: [ scoords: NB*CAP*16 | sidx: NB*CAP*4 | counts ]  ≈ 94.4 MB
    // (R5 proved ws >= 111 MB on this harness.)
    size_t scoords_b = (size_t)NB * CAP * 16;        // 75.5 MB
    size_t sidx_b    = (size_t)NB * CAP * 4;         // 18.9 MB
    size_t counts_b  = (size_t)NB * CPAD * 4;        // 37 KB
    size_t required  = scoords_b + sidx_b + counts_b + 256;

    if (d_ws == nullptr || ws_size < required) {
        int grid = (n + 255) / 256;
        direct_kernel<<<grid, 256, 0, stream>>>(coords, frames, out, n);
        return;
    }

    float4* scoords = (float4*)d_ws;
    int*    sidx    = (int*)((char*)d_ws + scoords_b);
    int*    counts  = (int*)((char*)d_ws + scoords_b + sidx_b);

    // Pass 0: zero counters (graph-replay idempotent).
    zero_counts_kernel<<<1, 1024, 0, stream>>>(counts);

    // Pass 1: fused binning (records + original index; no rank array).
    int bin_grid = (n + 256 * IPT - 1) / (256 * IPT);
    bin_kernel<<<bin_grid, 256, 0, stream>>>(coords, n, counts, scoords, sidx,
                                             frames, out);

    // Pass 2: locality-ordered sampling with direct scatter-out.
    main_kernel<<<NB * MBPB, 256, 0, stream>>>(scoords, sidx, counts, frames, out);
}

// Round 12
// 966.093 us; speedup vs baseline: 1.2549x; 1.2549x over previous
//
#include <hip/hip_runtime.h>

// Volume dims (fixed by the reference): frames[T=3][Z=72][Y=512][X=1024], fp32.
#define TT 3
#define ZZ 72
#define YY 512
#define XX 1024
#define FRAME_STRIDE ((long)ZZ * YY * XX)   // 37,748,736 elements
#define ZSTRIDE      ((long)YY * XX)        // 524,288
#define YSTRIDE      ((long)XX)             // 1,024

// Bucketing: key = z0 * 8 + (y0 >> 6)  → 72 * 8 = 576 buckets.
// Window per bucket: 2 z-slabs × 65 y-rows × 1024 x × 3 frames ≈ 1.6 MB.
#define NB    576
// Fixed slots per bucket. Uniform mean = N/NB = 7282, sd ≈ 85 → 8192 = +10.7σ.
// Overflow items are sampled INLINE in the bin pass (correct for any distribution).
#define CAP   8192
#define MBPB  (CAP / 256)   // main-pass blocks per bucket = 32
// One global counter per 64B line.
#define CPAD  16
#define IPT   16            // items per thread in the bin pass
#define WARM  1             // sequential pre-touch of each bucket's fresh slab

// R11 post-mortem: NT stores on scattered 16B records caused 3.4x write
// amplification (WRITE_SIZE 95->320 MB, bin 383 us, VALUBusy 0.8%).
// Scattered stores NEED L2 write-combining — all accesses are plain now.

// ---------------------------------------------------------------------------
// Pair-load trilerp: x0/x1 are adjacent → 4 float2 loads per frame instead of
// 8 scalar gathers (main is request-throughput-bound: 28% BW, 6% VALU).
// x0 == XX-1 (wx == 0): load at XX-2, use .y for both taps — exact ref math.
// ---------------------------------------------------------------------------
__device__ __forceinline__ float2 ld2(const float* __restrict__ p) {
    float2 v;
    __builtin_memcpy(&v, p, sizeof(float2));   // 4B-aligned 8B load (gfx950 ok)
    return v;
}

__device__ __forceinline__ float trilerp_frame(
    const float* __restrict__ fr,
    long oz0y0, long oz0y1, long oz1y0, long oz1y1,
    int xl, bool xhi, float wz, float wy, float wx)
{
    float2 a = ld2(fr + oz0y0 + xl);
    float2 b = ld2(fr + oz0y1 + xl);
    float2 c = ld2(fr + oz1y0 + xl);
    float2 d = ld2(fr + oz1y1 + xl);
    float c000 = xhi ? a.y : a.x, c001 = a.y;
    float c010 = xhi ? b.y : b.x, c011 = b.y;
    float c100 = xhi ? c.y : c.x, c101 = c.y;
    float c110 = xhi ? d.y : d.x, c111 = d.y;
    float iwx = 1.0f - wx;
    float c00 = c000 * iwx + c001 * wx;
    float c01 = c010 * iwx + c011 * wx;
    float c10 = c100 * iwx + c101 * wx;
    float c11 = c110 * iwx + c111 * wx;
    float iwy = 1.0f - wy;
    float c0 = c00 * iwy + c01 * wy;
    float c1 = c10 * iwy + c11 * wy;
    return c0 * (1.0f - wz) + c1 * wz;
}

__device__ __forceinline__ float sample_one(float4 c, const float* __restrict__ frames)
{
    // temporal
    float t_abs = c.w * 3.0f;
    int t0 = (int)floorf(t_abs);
    t0 = min(max(t0, 0), TT - 1);
    float w = t_abs - (float)t0;
    int t1 = min(t0 + 1, TT - 1);

    // spatial
    float sz = c.x * (float)(ZZ - 1);
    float sy = c.y * (float)(YY - 1);
    float sx = c.z * (float)(XX - 1);
    int z0 = (int)sz;
    int y0 = (int)sy;
    int x0 = (int)sx;
    float wz = sz - (float)z0;   // weights from UNclamped idx (ref semantics)
    float wy = sy - (float)y0;
    float wx = sx - (float)x0;
    z0 = min(max(z0, 0), ZZ - 1);
    y0 = min(max(y0, 0), YY - 1);
    x0 = min(max(x0, 0), XX - 1);
    int z1 = min(z0 + 1, ZZ - 1);
    int y1 = min(y0 + 1, YY - 1);

    int  xl  = min(x0, XX - 2);
    bool xhi = (x0 == XX - 1);

    long oz0y0 = (long)z0 * ZSTRIDE + (long)y0 * YSTRIDE;
    long oz0y1 = (long)z0 * ZSTRIDE + (long)y1 * YSTRIDE;
    long oz1y0 = (long)z1 * ZSTRIDE + (long)y0 * YSTRIDE;
    long oz1y1 = (long)z1 * ZSTRIDE + (long)y1 * YSTRIDE;

    const float* f0 = frames + (long)t0 * FRAME_STRIDE;
    float v0 = trilerp_frame(f0, oz0y0, oz0y1, oz1y0, oz1y1, xl, xhi, wz, wy, wx);

    float v1;
    if (t1 != t0) {
        const float* f1 = frames + (long)t1 * FRAME_STRIDE;
        v1 = trilerp_frame(f1, oz0y0, oz0y1, oz1y0, oz1y1, xl, xhi, wz, wy, wx);
    } else {
        v1 = v0;   // t_abs in [2,3): both samples identical — skip 4 pair-loads
    }
    return v0 * (1.0f - w) + v1 * w;
}

__device__ __forceinline__ int bucket_key(float4 c)
{
    int z0 = (int)(c.x * (float)(ZZ - 1));
    int y0 = (int)(c.y * (float)(YY - 1));
    z0 = min(max(z0, 0), ZZ - 1);
    y0 = min(max(y0, 0), YY - 1);
    return z0 * 8 + (y0 >> 6);
}

// ---------------------------------------------------------------------------
// Pass 0: zero the padded counters (capture-safe, replay-idempotent).
// ---------------------------------------------------------------------------
__global__ __launch_bounds__(1024) void zero_counts_kernel(int* __restrict__ counts)
{
    int t = threadIdx.x;
    if (t < NB) counts[t * CPAD] = 0;
}

// ---------------------------------------------------------------------------
// Pass 1: fused binning. Stores the full coord record + original index per
// slot (both read SEQUENTIALLY by main — no coords re-gather, no rank array,
// no permute pass). PLAIN stores: L2 write-combines the scattered 16B/4B
// records (R11: NT stores here = 3.4x write amplification, +40 us).
// Overflow (slot >= CAP): sample inline.
// ---------------------------------------------------------------------------
__global__ __launch_bounds__(256) void bin_kernel(
    const float4* __restrict__ coords, int n,
    int*    __restrict__ counts,     // NB padded counters (zeroed by pass 0)
    float4* __restrict__ scoords,    // NB*CAP coord records
    int*    __restrict__ sidx,       // NB*CAP original indices
    const float* __restrict__ frames, float* __restrict__ out)
{
    __shared__ int lcnt[NB];
    __shared__ int lbase[NB];
    for (int k = threadIdx.x; k < NB; k += 256) lcnt[k] = 0;
    __syncthreads();

    int base_i = blockIdx.x * (256 * IPT) + threadIdx.x;
    float4 cs[IPT];
    int keys[IPT];
    int ranks[IPT];
#pragma unroll
    for (int j = 0; j < IPT; ++j) {
        int i = base_i + j * 256;
        if (i < n) {
            cs[j]    = coords[i];
            keys[j]  = bucket_key(cs[j]);
            ranks[j] = atomicAdd(&lcnt[keys[j]], 1);
        }
    }
    __syncthreads();
    for (int k = threadIdx.x; k < NB; k += 256) {
        int c = lcnt[k];
        lbase[k] = c ? atomicAdd(&counts[k * CPAD], c) : 0;
    }
    __syncthreads();
#pragma unroll
    for (int j = 0; j < IPT; ++j) {
        int i = base_i + j * 256;
        if (i < n) {
            int s = lbase[keys[j]] + ranks[j];
            if (s < CAP) {
                int g = keys[j] * CAP + s;
                scoords[g] = cs[j];
                sidx[g]    = i;
            } else {
                out[i] = sample_one(cs[j], frames);   // cold path
            }
        }
    }
}

// ---------------------------------------------------------------------------
// Pass 2: sampling in bucket order. Each bucket's 32 blocks sequentially
// pre-touch a disjoint 1/32 slice of the bucket's FRESH slab (zg+1, 3 frames,
// 64 rows = 768 KB) — sequentializes the HBM first-touch stream (R5: 440→342
// with this + sequential records). Then sample records sequentially (plain
// loads — R5-verified config) and scatter out[sidx[g]] directly.
// ---------------------------------------------------------------------------
__global__ __launch_bounds__(256) void main_kernel(
    const float4* __restrict__ scoords, const int* __restrict__ sidx,
    const int*    __restrict__ counts,  const float* __restrict__ frames,
    float* __restrict__ out)
{
    int nwg  = gridDim.x;                 // NB*MBPB = 18432 (divisible by 8)
    int orig = blockIdx.x;
    int xcd  = orig & 7;
    int q = nwg >> 3, r = nwg & 7;
    int wg = (xcd < r ? xcd * (q + 1) : r * (q + 1) + (xcd - r) * q) + (orig >> 3);

    int bucket = wg / MBPB;
    int br     = wg % MBPB;               // this block's rank within the bucket

#if WARM
    {
        int zg = bucket >> 3;
        int yg = bucket & 7;
        int zs = (zg + 1 < ZZ) ? (zg + 1) : (ZZ - 1);
        float acc = 0.0f;
        int npass = (zg == 0) ? 2 : 1;    // z=0 buckets also warm slab 0
        for (int pass = 0; pass < npass; ++pass) {
            int zslab = pass ? 0 : zs;
            // fresh region: 3 frames x 64 rows x 256 float4 = 49152 float4
            // slice br: 1536 float4; per thread: 6
#pragma unroll
            for (int k = 0; k < 6; ++k) {
                int idx4 = br * 1536 + k * 256 + (int)threadIdx.x;
                int f    = idx4 >> 14;          // / (64*256)
                int rem  = idx4 & 16383;
                int ry   = rem >> 8;
                int c4   = rem & 255;
                const float* p = frames + (long)f * FRAME_STRIDE
                               + (long)zslab * ZSTRIDE
                               + (long)(yg * 64 + ry) * YSTRIDE
                               + (long)(c4 * 4);
                float4 v = *(const float4*)p;
                acc += v.x + v.y + v.z + v.w;
            }
        }
        asm volatile("" :: "v"(acc));       // keep warm loads live
    }
#endif

    int cnt = min(counts[bucket * CPAD], CAP);
    int slot = br * 256 + threadIdx.x;
    if (slot >= cnt) return;

    int g = bucket * CAP + slot;
    float4 c = scoords[g];
    int    j = sidx[g];
    out[j] = sample_one(c, frames);
}

// ---------------------------------------------------------------------------
// Fallback: direct kernel (used only if workspace missing/too small).
// ---------------------------------------------------------------------------
__global__ __launch_bounds__(256) void direct_kernel(
    const float4* __restrict__ coords, const float* __restrict__ frames,
    float* __restrict__ out, int n)
{
    int i = blockIdx.x * blockDim.x + threadIdx.x;
    if (i >= n) return;
    out[i] = sample_one(coords[i], frames);
}

extern "C" void kernel_launch(void* const* d_in, const int* in_sizes, int n_in,
                              void* d_out, int out_size, void* d_ws, size_t ws_size,
                              hipStream_t stream) {
    const float4* coords = (const float4*)d_in[0];   // N*4 floats
    const float*  frames = (const float*)d_in[1];    // T*Z*Y*X floats
    float* out = (float*)d_out;                      // N floats
    int n = in_sizes[0] / 4;

    // Workspace: [ scoords: NB*CAP*16 | sidx: NB*CAP*4 | counts ]  ≈ 94.4 MB
    // (R5 proved ws >= 111 MB on this harness.)
    size_t scoords_b = (size_t)NB * CAP * 16;        // 75.5 MB
    size_t sidx_b    = (size_t)NB * CAP * 4;         // 18.9 MB
    size_t counts_b  = (size_t)NB * CPAD * 4;        // 37 KB
    size_t required  = scoords_b + sidx_b + counts_b + 256;

    if (d_ws == nullptr || ws_size < required) {
        int grid = (n + 255) / 256;
        direct_kernel<<<grid, 256, 0, stream>>>(coords, frames, out, n);
        return;
    }

    float4* scoords = (float4*)d_ws;
    int*    sidx    = (int*)((char*)d_ws + scoords_b);
    int*    counts  = (int*)((char*)d_ws + scoords_b + sidx_b);

    // Pass 0: zero counters (graph-replay idempotent).
    zero_counts_kernel<<<1, 1024, 0, stream>>>(counts);

    // Pass 1: fused binning (records + original index; no rank array).
    int bin_grid = (n + 256 * IPT - 1) / (256 * IPT);
    bin_kernel<<<bin_grid, 256, 0, stream>>>(coords, n, counts, scoords, sidx,
                                             frames, out);

    // Pass 2: locality-ordered sampling with direct scatter-out.
    main_kernel<<<NB * MBPB, 256, 0, stream>>>(scoords, sidx, counts, frames, out);
}

// Round 13
// 924.915 us; speedup vs baseline: 1.3108x; 1.0445x over previous
//
#include <hip/hip_runtime.h>

// Volume dims (fixed by the reference): frames[T=3][Z=72][Y=512][X=1024], fp32.
#define TT 3
#define ZZ 72
#define YY 512
#define XX 1024
#define FRAME_STRIDE ((long)ZZ * YY * XX)   // 37,748,736 elements
#define ZSTRIDE      ((long)YY * XX)        // 524,288
#define YSTRIDE      ((long)XX)             // 1,024

// Bucketing: key = z0 * 8 + (y0 >> 6)  → 72 * 8 = 576 buckets.
// Window per bucket: 2 z-slabs × 65 y-rows × 1024 x × 3 frames ≈ 1.6 MB (fits 4MiB XCD L2).
#define NB    576
#define CAP   8192          // slots/bucket; mean 7282, +10.7 sigma; overflow sampled inline
#define MBPB  (CAP / 256)   // main-pass blocks per bucket = 32
#define CPAD  16            // one global counter per 64B line
#define IPT   16            // items per thread in the bin pass
#define WARM  1

// R12 post-mortem: main FETCH=861MB vs ~570 compulsory. Cause: z-outermost
// bucket sweep touches 12.6MB (2 slabs x all-y) per z before moving on — 3x
// the 4MiB XCD L2 — so every slab is fetched ~2x. Fix: z-INNERMOST sweep,
// one 64-row y-stripe per XCD; the 2-slab window (1.6MB) slides down z and
// every 786KB slab-stripe block is fetched once, reused once.

// ---------------------------------------------------------------------------
// Pair-load trilerp (R12-verified): 4 float2 loads per frame, exact ref math.
// ---------------------------------------------------------------------------
__device__ __forceinline__ float2 ld2(const float* __restrict__ p) {
    float2 v;
    __builtin_memcpy(&v, p, sizeof(float2));
    return v;
}

__device__ __forceinline__ float trilerp_frame(
    const float* __restrict__ fr,
    long oz0y0, long oz0y1, long oz1y0, long oz1y1,
    int xl, bool xhi, float wz, float wy, float wx)
{
    float2 a = ld2(fr + oz0y0 + xl);
    float2 b = ld2(fr + oz0y1 + xl);
    float2 c = ld2(fr + oz1y0 + xl);
    float2 d = ld2(fr + oz1y1 + xl);
    float c000 = xhi ? a.y : a.x, c001 = a.y;
    float c010 = xhi ? b.y : b.x, c011 = b.y;
    float c100 = xhi ? c.y : c.x, c101 = c.y;
    float c110 = xhi ? d.y : d.x, c111 = d.y;
    float iwx = 1.0f - wx;
    float c00 = c000 * iwx + c001 * wx;
    float c01 = c010 * iwx + c011 * wx;
    float c10 = c100 * iwx + c101 * wx;
    float c11 = c110 * iwx + c111 * wx;
    float iwy = 1.0f - wy;
    float c0 = c00 * iwy + c01 * wy;
    float c1 = c10 * iwy + c11 * wy;
    return c0 * (1.0f - wz) + c1 * wz;
}

__device__ __forceinline__ float sample_one(float4 c, const float* __restrict__ frames)
{
    float t_abs = c.w * 3.0f;
    int t0 = (int)floorf(t_abs);
    t0 = min(max(t0, 0), TT - 1);
    float w = t_abs - (float)t0;
    int t1 = min(t0 + 1, TT - 1);

    float sz = c.x * (float)(ZZ - 1);
    float sy = c.y * (float)(YY - 1);
    float sx = c.z * (float)(XX - 1);
    int z0 = (int)sz;
    int y0 = (int)sy;
    int x0 = (int)sx;
    float wz = sz - (float)z0;   // weights from UNclamped idx (ref semantics)
    float wy = sy - (float)y0;
    float wx = sx - (float)x0;
    z0 = min(max(z0, 0), ZZ - 1);
    y0 = min(max(y0, 0), YY - 1);
    x0 = min(max(x0, 0), XX - 1);
    int z1 = min(z0 + 1, ZZ - 1);
    int y1 = min(y0 + 1, YY - 1);

    int  xl  = min(x0, XX - 2);
    bool xhi = (x0 == XX - 1);

    long oz0y0 = (long)z0 * ZSTRIDE + (long)y0 * YSTRIDE;
    long oz0y1 = (long)z0 * ZSTRIDE + (long)y1 * YSTRIDE;
    long oz1y0 = (long)z1 * ZSTRIDE + (long)y0 * YSTRIDE;
    long oz1y1 = (long)z1 * ZSTRIDE + (long)y1 * YSTRIDE;

    const float* f0 = frames + (long)t0 * FRAME_STRIDE;
    float v0 = trilerp_frame(f0, oz0y0, oz0y1, oz1y0, oz1y1, xl, xhi, wz, wy, wx);

    float v1;
    if (t1 != t0) {
        const float* f1 = frames + (long)t1 * FRAME_STRIDE;
        v1 = trilerp_frame(f1, oz0y0, oz0y1, oz1y0, oz1y1, xl, xhi, wz, wy, wx);
    } else {
        v1 = v0;
    }
    return v0 * (1.0f - w) + v1 * w;
}

__device__ __forceinline__ int bucket_key(float4 c)
{
    int z0 = (int)(c.x * (float)(ZZ - 1));
    int y0 = (int)(c.y * (float)(YY - 1));
    z0 = min(max(z0, 0), ZZ - 1);
    y0 = min(max(y0, 0), YY - 1);
    return z0 * 8 + (y0 >> 6);
}

// ---------------------------------------------------------------------------
// Pass 0: zero the padded counters.
// ---------------------------------------------------------------------------
__global__ __launch_bounds__(1024) void zero_counts_kernel(int* __restrict__ counts)
{
    int t = threadIdx.x;
    if (t < NB) counts[t * CPAD] = 0;
}

// ---------------------------------------------------------------------------
// Pass 1: fused binning (UNCHANGED from R12 — control for attribution).
// Plain stores; L2 write-combines the scattered records (R11 NT lesson).
// ---------------------------------------------------------------------------
__global__ __launch_bounds__(256) void bin_kernel(
    const float4* __restrict__ coords, int n,
    int*    __restrict__ counts,
    float4* __restrict__ scoords,
    int*    __restrict__ sidx,
    const float* __restrict__ frames, float* __restrict__ out)
{
    __shared__ int lcnt[NB];
    __shared__ int lbase[NB];
    for (int k = threadIdx.x; k < NB; k += 256) lcnt[k] = 0;
    __syncthreads();

    int base_i = blockIdx.x * (256 * IPT) + threadIdx.x;
    float4 cs[IPT];
    int keys[IPT];
    int ranks[IPT];
#pragma unroll
    for (int j = 0; j < IPT; ++j) {
        int i = base_i + j * 256;
        if (i < n) {
            cs[j]    = coords[i];
            keys[j]  = bucket_key(cs[j]);
            ranks[j] = atomicAdd(&lcnt[keys[j]], 1);
        }
    }
    __syncthreads();
    for (int k = threadIdx.x; k < NB; k += 256) {
        int c = lcnt[k];
        lbase[k] = c ? atomicAdd(&counts[k * CPAD], c) : 0;
    }
    __syncthreads();
#pragma unroll
    for (int j = 0; j < IPT; ++j) {
        int i = base_i + j * 256;
        if (i < n) {
            int s = lbase[keys[j]] + ranks[j];
            if (s < CAP) {
                int g = keys[j] * CAP + s;
                scoords[g] = cs[j];
                sidx[g]    = i;
            } else {
                out[i] = sample_one(cs[j], frames);   // cold path
            }
        }
    }
}

// ---------------------------------------------------------------------------
// Pass 2: sampling, z-innermost sweep. XCD k owns y-stripe k (2304 wgs =
// 72 z-levels x 32 blocks). Decode: stripe = wg/2304, z = (wg%2304)/32,
// br = wg%32; bucket = z*8 + stripe. The 2-slab window slides down z and
// stays L2-resident. Warming pre-touches the FRESH slab z+1 sequentially.
// ---------------------------------------------------------------------------
__global__ __launch_bounds__(256) void main_kernel(
    const float4* __restrict__ scoords, const int* __restrict__ sidx,
    const int*    __restrict__ counts,  const float* __restrict__ frames,
    float* __restrict__ out)
{
    int nwg  = gridDim.x;                 // NB*MBPB = 18432 (divisible by 8)
    int orig = blockIdx.x;
    int xcd  = orig & 7;
    int q = nwg >> 3, r = nwg & 7;
    int wg = (xcd < r ? xcd * (q + 1) : r * (q + 1) + (xcd - r) * q) + (orig >> 3);

    int stripe = wg / (72 * MBPB);        // y-group, one per XCD
    int rem    = wg % (72 * MBPB);
    int z      = rem / MBPB;              // z-level, innermost
    int br     = rem % MBPB;              // block rank within bucket
    int bucket = z * 8 + stripe;          // storage id (matches bin's key)

#if WARM
    {
        int zs = (z + 1 < ZZ) ? (z + 1) : (ZZ - 1);
        float acc = 0.0f;
        int npass = (z == 0) ? 2 : 1;     // z=0 buckets also warm slab 0
        for (int pass = 0; pass < npass; ++pass) {
            int zslab = pass ? 0 : zs;
            // fresh region: 3 frames x 64 rows x 256 float4 = 49152 float4
            // slice br: 1536 float4; per thread: 6
#pragma unroll
            for (int k = 0; k < 6; ++k) {
                int idx4 = br * 1536 + k * 256 + (int)threadIdx.x;
                int f    = idx4 >> 14;          // / (64*256)
                int rrem = idx4 & 16383;
                int ry   = rrem >> 8;
                int c4   = rrem & 255;
                const float* p = frames + (long)f * FRAME_STRIDE
                               + (long)zslab * ZSTRIDE
                               + (long)(stripe * 64 + ry) * YSTRIDE
                               + (long)(c4 * 4);
                float4 v = *(const float4*)p;
                acc += v.x + v.y + v.z + v.w;
            }
        }
        asm volatile("" :: "v"(acc));       // keep warm loads live
    }
#endif

    int cnt = min(counts[bucket * CPAD], CAP);
    int slot = br * 256 + threadIdx.x;
    if (slot >= cnt) return;

    int g = bucket * CAP + slot;
    float4 c = scoords[g];
    int    j = sidx[g];
    out[j] = sample_one(c, frames);
}

// ---------------------------------------------------------------------------
// Fallback: direct kernel (workspace missing/too small).
// ---------------------------------------------------------------------------
__global__ __launch_bounds__(256) void direct_kernel(
    const float4* __restrict__ coords, const float* __restrict__ frames,
    float* __restrict__ out, int n)
{
    int i = blockIdx.x * blockDim.x + threadIdx.x;
    if (i >= n) return;
    out[i] = sample_one(coords[i], frames);
}

extern "C" void kernel_launch(void* const* d_in, const int* in_sizes, int n_in,
                              void* d_out, int out_size, void* d_ws, size_t ws_size,
                              hipStream_t stream) {
    const float4* coords = (const float4*)d_in[0];   // N*4 floats
    const float*  frames = (const float*)d_in[1];    // T*Z*Y*X floats
    float* out = (float*)d_out;                      // N floats
    int n = in_sizes[0] / 4;

    // Workspace: [ scoords: NB*CAP*16 | sidx: NB*CAP*4 | counts ]  ≈ 94.4 MB
    size_t scoords_b = (size_t)NB * CAP * 16;
    size_t sidx_b    = (size_t)NB * CAP * 4;
    size_t counts_b  = (size_t)NB * CPAD * 4;
    size_t required  = scoords_b + sidx_b + counts_b + 256;

    if (d_ws == nullptr || ws_size < required) {
        int grid = (n + 255) / 256;
        direct_kernel<<<grid, 256, 0, stream>>>(coords, frames, out, n);
        return;
    }

    float4* scoords = (float4*)d_ws;
    int*    sidx    = (int*)((char*)d_ws + scoords_b);
    int*    counts  = (int*)((char*)d_ws + scoords_b + sidx_b);

    zero_counts_kernel<<<1, 1024, 0, stream>>>(counts);

    int bin_grid = (n + 256 * IPT - 1) / (256 * IPT);
    bin_kernel<<<bin_grid, 256, 0, stream>>>(coords, n, counts, scoords, sidx,
                                             frames, out);

    main_kernel<<<NB * MBPB, 256, 0, stream>>>(scoords, sidx, counts, frames, out);
}